// Round 5
// baseline (186.758 us; speedup 1.0000x reference)
//
#include <hip/hip_runtime.h>

#define BLK 256
#define PD 64
#define PI_F 3.14159265358979323846f

__device__ __forceinline__ float fast_tanh(float v) {
    float e = __expf(2.0f * v);
    return 1.0f - 2.0f / (e + 1.0f);
}

// Apply 2x2 complex gate to qubit mask M over 16 amps (new_i = sum_j U[i][j] old_j).
template<int M>
__device__ __forceinline__ void gate_apply(float* ar, float* ai,
        float u00r, float u00i, float u01r, float u01i,
        float u10r, float u10i, float u11r, float u11i) {
    #pragma unroll
    for (int i = 0; i < 16; ++i) {
        if (i & M) continue;
        const int j = i | M;
        const float a0r = ar[i], a0i = ai[i], a1r = ar[j], a1i = ai[j];
        ar[i] = u00r*a0r - u00i*a0i + u01r*a1r - u01i*a1i;
        ai[i] = u00r*a0i + u00i*a0r + u01r*a1i + u01i*a1r;
        ar[j] = u10r*a0r - u10i*a0i + u11r*a1r - u11i*a1i;
        ai[j] = u10r*a0i + u10i*a0r + u11r*a1i + u11i*a1r;
    }
}

template<int CM, int TM>
__device__ __forceinline__ void cnotg(float* ar, float* ai) {
    #pragma unroll
    for (int i = 0; i < 16; ++i) {
        if ((i & CM) && !(i & TM)) {
            const int j = i | TM;
            float tp;
            tp = ar[i]; ar[i] = ar[j]; ar[j] = tp;
            tp = ai[i]; ai[i] = ai[j]; ai[j] = tp;
        }
    }
}

// ---- prep: 1 block x 64 threads. ws[0..63] = 8 gates x 8 coeffs;
//      ws[64..83] = LN moments {M(10 sym), v(4), Wbar(4), bbar, bsq} ----
extern "C" __global__ void __launch_bounds__(64)
qbranch_prep(const float* __restrict__ wts, const float* __restrict__ W,
             const float* __restrict__ bias, float* __restrict__ ws)
{
    const int t = threadIdx.x;
    const float4 wr = reinterpret_cast<const float4*>(W)[t];
    const float bp = bias[t];
    float v[20] = { wr.x*wr.x, wr.x*wr.y, wr.x*wr.z, wr.x*wr.w,
                    wr.y*wr.y, wr.y*wr.z, wr.y*wr.w,
                    wr.z*wr.z, wr.z*wr.w,
                    wr.w*wr.w,
                    wr.x*bp, wr.y*bp, wr.z*bp, wr.w*bp,
                    wr.x, wr.y, wr.z, wr.w,
                    bp, bp*bp };
    #pragma unroll
    for (int o = 32; o > 0; o >>= 1) {
        #pragma unroll
        for (int k = 0; k < 20; ++k) v[k] += __shfl_xor(v[k], o, 64);
    }
    if (t == 0) {
        #pragma unroll
        for (int k = 0; k < 20; ++k) ws[64 + k] = v[k] * (1.0f / 64.0f);
    }
    if (t < 8) {
        const float phi = wts[t * 3 + 0];
        const float th  = wts[t * 3 + 1];
        const float om  = wts[t * 3 + 2];
        float st, ct;  __sincosf(0.5f * th, &st, &ct);
        float sa, ca;  __sincosf(0.5f * (phi + om), &sa, &ca);
        float sb, cb;  __sincosf(0.5f * (phi - om), &sb, &cb);
        float* gg = ws + t * 8;
        gg[0] =  ct * ca;  gg[1] = -ct * sa;   // u00 = ep*ct
        gg[2] = -st * cb;  gg[3] = -st * sb;   // u01 = -conj(em)*st
        gg[4] =  st * cb;  gg[5] = -st * sb;   // u10 = em*st
        gg[6] =  ct * ca;  gg[7] =  ct * sa;   // u11 = conj(ep)*ct
    }
}

// ---- kernel A: circuit only. One thread per batch element; writes q (float4)
//      and (mu, rstd) (float2). No LDS, no barrier, low VGPR pressure. ----
extern "C" __global__ void __launch_bounds__(BLK)
qbranch_circuit(const float* __restrict__ x,    // (B,4)
                const float* __restrict__ cw,   // gates + moments
                float4* __restrict__ wq,        // (B) q
                float2* __restrict__ wms)       // (B) mu,rstd
{
    const int b = blockIdx.x * BLK + threadIdx.x;
    const float4 xv = reinterpret_cast<const float4*>(x)[b];

    // RX 2-vector per qubit with layer-0 rot folded in (product state).
    float v0r[4], v0i[4], v1r[4], v1i[4];
    const float xs[4] = {xv.x, xv.y, xv.z, xv.w};
    #pragma unroll
    for (int w = 0; w < 4; ++w) {
        float s, c;
        __sincosf(0.5f * PI_F * fast_tanh(xs[w]), &s, &c);
        const float g0 = cw[w*8+0], g1 = cw[w*8+1], g2 = cw[w*8+2], g3 = cw[w*8+3];
        const float g4 = cw[w*8+4], g5 = cw[w*8+5], g6 = cw[w*8+6], g7 = cw[w*8+7];
        v0r[w] = fmaf(c, g0,  s * g3);
        v0i[w] = fmaf(c, g1, -s * g2);
        v1r[w] = fmaf(c, g4,  s * g7);
        v1i[w] = fmaf(c, g5, -s * g6);
    }

    // 16-amp state via pairwise tensor products (compile-time selects).
    float Ar[4], Ai[4], Br[4], Bi[4];
    #pragma unroll
    for (int j = 0; j < 4; ++j) {
        const int b0 = j >> 1, b1 = j & 1;
        const float p0r = b0 ? v1r[0] : v0r[0], p0i = b0 ? v1i[0] : v0i[0];
        const float p1r = b1 ? v1r[1] : v0r[1], p1i = b1 ? v1i[1] : v0i[1];
        Ar[j] = p0r*p1r - p0i*p1i;
        Ai[j] = p0r*p1i + p0i*p1r;
        const float p2r = b0 ? v1r[2] : v0r[2], p2i = b0 ? v1i[2] : v0i[2];
        const float p3r = b1 ? v1r[3] : v0r[3], p3i = b1 ? v1i[3] : v0i[3];
        Br[j] = p2r*p3r - p2i*p3i;
        Bi[j] = p2r*p3i + p2i*p3r;
    }
    float ar[16], ai[16];
    #pragma unroll
    for (int i = 0; i < 16; ++i) {
        const int hi = i >> 2, lo = i & 3;
        ar[i] = Ar[hi]*Br[lo] - Ai[hi]*Bi[lo];
        ai[i] = Ar[hi]*Bi[lo] + Ai[hi]*Br[lo];
    }

    // CNOT ring r=1: (0,1),(1,2),(2,3),(3,0)
    cnotg<8, 4>(ar, ai);
    cnotg<4, 2>(ar, ai);
    cnotg<2, 1>(ar, ai);
    cnotg<1, 8>(ar, ai);

    // Layer-1 rot gates (coeffs are scalar/uniform operands).
    gate_apply<8>(ar, ai, cw[32], cw[33], cw[34], cw[35], cw[36], cw[37], cw[38], cw[39]);
    gate_apply<4>(ar, ai, cw[40], cw[41], cw[42], cw[43], cw[44], cw[45], cw[46], cw[47]);
    gate_apply<2>(ar, ai, cw[48], cw[49], cw[50], cw[51], cw[52], cw[53], cw[54], cw[55]);
    gate_apply<1>(ar, ai, cw[56], cw[57], cw[58], cw[59], cw[60], cw[61], cw[62], cw[63]);

    // CNOT ring r=2: (0,2),(1,3),(2,0),(3,1)
    cnotg<8, 2>(ar, ai);
    cnotg<4, 1>(ar, ai);
    cnotg<2, 8>(ar, ai);
    cnotg<1, 4>(ar, ai);

    // Z expectations, softmax
    float z0 = 0.f, z1 = 0.f, z2 = 0.f, z3 = 0.f;
    #pragma unroll
    for (int i = 0; i < 16; ++i) {
        const float p = ar[i]*ar[i] + ai[i]*ai[i];
        z0 += (i & 8) ? -p : p;
        z1 += (i & 4) ? -p : p;
        z2 += (i & 2) ? -p : p;
        z3 += (i & 1) ? -p : p;
    }
    const float mx = fmaxf(fmaxf(z0, z1), fmaxf(z2, z3));
    const float e0 = __expf(z0 - mx), e1 = __expf(z1 - mx);
    const float e2 = __expf(z2 - mx), e3 = __expf(z3 - mx);
    const float inv = 1.0f / (e0 + e1 + e2 + e3);
    const float q0 = e0 * inv, q1 = e1 * inv, q2 = e2 * inv, q3 = e3 * inv;

    // LN stats via moments: mu = q.Wbar + bbar; E[h^2] = q^T M q + 2 q.v + bsq
    const float* sS = cw + 64;
    const float mu = fmaf(q0, sS[14], fmaf(q1, sS[15], fmaf(q2, sS[16], fmaf(q3, sS[17], sS[18]))));
    const float t0 = sS[0]*q0 + sS[1]*q1 + sS[2]*q2 + sS[3]*q3 + 2.0f*sS[10];
    const float t1 = sS[1]*q0 + sS[4]*q1 + sS[5]*q2 + sS[6]*q3 + 2.0f*sS[11];
    const float t2 = sS[2]*q0 + sS[5]*q1 + sS[7]*q2 + sS[8]*q3 + 2.0f*sS[12];
    const float t3 = sS[3]*q0 + sS[6]*q1 + sS[8]*q2 + sS[9]*q3 + 2.0f*sS[13];
    const float Eh2 = t0*q0 + t1*q1 + t2*q2 + t3*q3 + sS[19];
    const float rstd = rsqrtf(Eh2 - mu * mu + 1e-5f);

    wq[b]  = make_float4(q0, q1, q2, q3);
    wms[b] = make_float2(mu, rstd);
}

// ---- kernel B: streaming epilogue. Block covers 256 rows; thread owns
//      cols (t&15)*4.. and rows it*16+(t>>4) over 16 iters. q/ms loads are
//      16-lane broadcasts (L2/LLC); each wave stores 1 KB contiguous/iter. ----
extern "C" __global__ void __launch_bounds__(BLK)
qbranch_epilogue(const float4* __restrict__ wq,
                 const float2* __restrict__ wms,
                 const float* __restrict__ W,      // (64,4)
                 const float* __restrict__ bias,   // (64)
                 const float* __restrict__ gamma,  // (64)
                 const float* __restrict__ beta,   // (64)
                 float* __restrict__ out)          // (B,64)
{
    const int t = threadIdx.x;
    const int p4 = t & 15;
    const int sub = t >> 4;          // 0..15
    const int row0 = blockIdx.x * BLK;

    const float4 w0 = reinterpret_cast<const float4*>(W)[p4 * 4 + 0];
    const float4 w1 = reinterpret_cast<const float4*>(W)[p4 * 4 + 1];
    const float4 w2 = reinterpret_cast<const float4*>(W)[p4 * 4 + 2];
    const float4 w3 = reinterpret_cast<const float4*>(W)[p4 * 4 + 3];
    const float4 bg = reinterpret_cast<const float4*>(bias)[p4];
    const float4 gm = reinterpret_cast<const float4*>(gamma)[p4];
    const float4 bt = reinterpret_cast<const float4*>(beta)[p4];

    const size_t base = (size_t)row0 * PD;
    #pragma unroll 4
    for (int it = 0; it < 16; ++it) {
        const int row = row0 + it * 16 + sub;
        const float4 qv = wq[row];
        const float2 ms = wms[row];
        const float h0 = fmaf(qv.x, w0.x, fmaf(qv.y, w0.y, fmaf(qv.z, w0.z, fmaf(qv.w, w0.w, bg.x))));
        const float h1 = fmaf(qv.x, w1.x, fmaf(qv.y, w1.y, fmaf(qv.z, w1.z, fmaf(qv.w, w1.w, bg.y))));
        const float h2 = fmaf(qv.x, w2.x, fmaf(qv.y, w2.y, fmaf(qv.z, w2.z, fmaf(qv.w, w2.w, bg.z))));
        const float h3 = fmaf(qv.x, w3.x, fmaf(qv.y, w3.y, fmaf(qv.z, w3.z, fmaf(qv.w, w3.w, bg.w))));
        float4 pk;
        pk.x = fmaf((h0 - ms.x), ms.y * gm.x, bt.x);
        pk.y = fmaf((h1 - ms.x), ms.y * gm.y, bt.y);
        pk.z = fmaf((h2 - ms.x), ms.y * gm.z, bt.z);
        pk.w = fmaf((h3 - ms.x), ms.y * gm.w, bt.w);
        *reinterpret_cast<float4*>(&out[base + (size_t)(it * 16 + sub) * PD + p4 * 4]) = pk;
    }
}

extern "C" void kernel_launch(void* const* d_in, const int* in_sizes, int n_in,
                              void* d_out, int out_size, void* d_ws, size_t ws_size,
                              hipStream_t stream) {
    const float* x     = (const float*)d_in[0];
    const float* wts   = (const float*)d_in[1];
    const float* W     = (const float*)d_in[2];
    const float* bias  = (const float*)d_in[3];
    const float* gamma = (const float*)d_in[4];
    const float* beta  = (const float*)d_in[5];
    float* ws  = (float*)d_ws;
    float* out = (float*)d_out;
    const int B = in_sizes[0] / 4;          // 524288

    float4* wq  = (float4*)(ws + 256);               // 16-B aligned, 8 MB
    float2* wms = (float2*)(ws + 256 + 4 * (size_t)B); // 8-B aligned, 4 MB

    hipLaunchKernelGGL(qbranch_prep, dim3(1), dim3(64), 0, stream, wts, W, bias, ws);
    hipLaunchKernelGGL(qbranch_circuit, dim3(B / BLK), dim3(BLK), 0, stream,
                       x, ws, wq, wms);
    hipLaunchKernelGGL(qbranch_epilogue, dim3(B / BLK), dim3(BLK), 0, stream,
                       wq, wms, W, bias, gamma, beta, out);
}